// Round 13
// baseline (25.633 us; speedup 1.0000x reference)
//
#include <hip/hip_runtime.h>
#include <math.h>

#define BLOCK 1024
#define CHUNK 256              // elements per chunk = BLOCK/4
#define MAXCH 8                // LDS window sized for up to 8 chunks (B <= 524288)
#define TAPS 16
#define HWIN 16                // s-window offset; slots 1..15 hold the block halo

__device__ __forceinline__ float eluf(float v) { return v > 0.f ? v : expm1f(v); }
__device__ __forceinline__ float dot4(float4 a, float4 b) {
    return a.x * b.x + a.y * b.y + a.z * b.z + a.w * b.w;
}

// 4-lane cooperative conv1+conv2 from 8 preloaded float4 (lane role j = t&3).
// Butterfly stays inside the aligned 4-lane quad. All 4 lanes end with (sr,si).
__device__ __forceinline__ void conv_from_regs(const float4* v,
        float4 wv0, float4 wv1, float b1s,
        const float* __restrict__ w2, float b20, float b21,
        float& sr, float& si)
{
    float a0 = dot4(v[0], wv0), a1 = dot4(v[1], wv0),
          a2 = dot4(v[2], wv0), a3 = dot4(v[3], wv0);
    a0 += dot4(v[4], wv1); a1 += dot4(v[5], wv1);
    a2 += dot4(v[6], wv1); a3 += dot4(v[7], wv1);

    a0 += __shfl_xor(a0, 1); a1 += __shfl_xor(a1, 1);
    a2 += __shfl_xor(a2, 1); a3 += __shfl_xor(a3, 1);
    a0 += __shfl_xor(a0, 2); a1 += __shfl_xor(a1, 2);
    a2 += __shfl_xor(a2, 2); a3 += __shfl_xor(a3, 2);

    float h0 = eluf(a0 + b1s), h1 = eluf(a1 + b1s);
    float h2 = eluf(a2 + b1s), h3 = eluf(a3 + b1s);

    sr = eluf(b20 + h0 * w2[0] + h1 * w2[1] + h2 * w2[2] + h3 * w2[3]);
    si = eluf(b21 + h0 * w2[4] + h1 * w2[5] + h2 * w2[6] + h3 * w2[7]);
}

__global__ __launch_bounds__(BLOCK, 4) void NF_20581483282566_kernel(
    const float* __restrict__ x,
    const float* __restrict__ w1, const float* __restrict__ b1,
    const float* __restrict__ w2, const float* __restrict__ b2,
    const float* __restrict__ tr, const float* __restrict__ ti,
    float2* __restrict__ out, int B, int span)
{
    __shared__ float s_r[HWIN + MAXCH * CHUNK];
    __shared__ float s_i[HWIN + MAXCH * CHUNK];
    __shared__ float s_tr[TAPS], s_ti[TAPS];

    const int t  = threadIdx.x;
    const int j  = t & 3;
    const int el = t >> 2;                      // 0..255, element slot in chunk

    const long span_start = (long)blockIdx.x * span;
    const long span_end   = min(span_start + (long)span, (long)B);
    if (span_start >= span_end) return;
    const int nch = (int)((span_end - span_start + CHUNK - 1) / CHUNK);

    const float4* xf4 = reinterpret_cast<const float4*>(x);
    const float4* w1v = reinterpret_cast<const float4*>(w1);
    const float4 wv0 = w1v[j];
    const float4 wv1 = w1v[4 + j];
    const float b1s = b1[0];
    const float b20 = b2[0], b21 = b2[1];

    // ---- prologue: issue chunk-0 loads, then halo loads; stage taps ----
    float4 v[8];
    bool own = (span_start + el) < span_end;    // chunk 0 ownership
    if (own) {
        const float4* base = xf4 + (span_start + el) * 32;
#pragma unroll
        for (int p = 0; p < 8; ++p) v[p] = base[4 * p + j];
    }
    if (t < TAPS) { s_tr[t] = tr[t]; s_ti[t] = ti[t]; }

    if (t < 60) {                               // 15 halo elements x 4 lanes
        const int  eh = t >> 2;                 // 0..14
        const long he = span_start - 15 + eh;
        float sr = 0.f, si = 0.f;
        if (he >= 0) {
            float4 hv[8];
            const float4* hbase = xf4 + he * 32;
#pragma unroll
            for (int p = 0; p < 8; ++p) hv[p] = hbase[4 * p + j];
            conv_from_regs(hv, wv0, wv1, b1s, w2, b20, b21, sr, si);
        }
        if (j == 0) { s_r[1 + eh] = sr; s_i[1 + eh] = si; }
    }

    // ---- chunk loop: loads(c+1) in flight during compute+FIR of c ----
    for (int c = 0; c < nch; ++c) {
        // issue next chunk's loads first
        float4 vn[8];
        bool own_n = false;
        if (c + 1 < nch) {
            const long gn = span_start + (long)(c + 1) * CHUNK + el;
            own_n = gn < span_end;
            if (own_n) {
                const float4* nbase = xf4 + gn * 32;
#pragma unroll
                for (int p = 0; p < 8; ++p) vn[p] = nbase[4 * p + j];
            }
        }

        // compute s for chunk c (waits on v's loads)
        if (own) {
            float sr, si;
            conv_from_regs(v, wv0, wv1, b1s, w2, b20, b21, sr, si);
            if (j == 0) {
                s_r[HWIN + c * CHUNK + el] = sr;
                s_i[HWIN + c * CHUNK + el] = si;
            }
        }
        __syncthreads();

        // FIR + store for chunk c (waves 0-3); other waves run ahead
        if (t < CHUNK) {
            const long b = span_start + (long)c * CHUNK + t;
            if (b < span_end) {
                const int idx = HWIN + c * CHUNK + t;
                float yr = 0.f, yi = 0.f;
#pragma unroll
                for (int jj = 0; jj < TAPS; ++jj) {
                    float a = s_r[idx - jj];
                    float cc = s_i[idx - jj];
                    float trj = s_tr[jj], tij = s_ti[jj];
                    yr += a * trj - cc * tij;
                    yi += a * tij + cc * trj;
                }
                out[b] = make_float2(yr, yi);
            }
        }

        // rotate pipeline registers
#pragma unroll
        for (int p = 0; p < 8; ++p) v[p] = vn[p];
        own = own_n;
    }
}

extern "C" void kernel_launch(void* const* d_in, const int* in_sizes, int n_in,
                              void* d_out, int out_size, void* d_ws, size_t ws_size,
                              hipStream_t stream) {
    const float* x  = (const float*)d_in[0];
    const float* w1 = (const float*)d_in[1];
    const float* b1 = (const float*)d_in[2];
    const float* w2 = (const float*)d_in[3];
    const float* b2 = (const float*)d_in[4];
    const float* tr = (const float*)d_in[5];
    const float* ti = (const float*)d_in[6];
    float2* out = (float2*)d_out;

    const int B = in_sizes[0] / 128;             // x is (B, 2, 64)
    const int grid = 256;                        // persistent: 1 block per CU
    int span = (B + grid - 1) / grid;            // elements per block
    // LDS window supports up to MAXCH chunks per block
    // (B=200000 -> span=782 -> 4 chunks)
    NF_20581483282566_kernel<<<grid, BLOCK, 0, stream>>>(x, w1, b1, w2, b2, tr, ti,
                                                         out, B, span);
}